// Round 9
// baseline (638.658 us; speedup 1.0000x reference)
//
#include <hip/hip_runtime.h>
#include <hip/hip_cooperative_groups.h>

namespace cg = cooperative_groups;

#define CH 128
#define BUILD_GRID 768   // 3 blocks/CU on 256 CUs — safe co-residency for coop launch

typedef short bf16x8 __attribute__((ext_vector_type(8)));
typedef float f32x4 __attribute__((ext_vector_type(4)));
typedef unsigned short u16x8 __attribute__((ext_vector_type(8)));

static __device__ __forceinline__ unsigned short f2bf(float f) {
    unsigned int u = __float_as_uint(f);
    u = (u + 0x7fff + ((u >> 16) & 1)) >> 16;   // RNE
    return (unsigned short)u;
}
static __device__ __forceinline__ float bf2f(unsigned short s) {
    return __uint_as_float(((unsigned int)s) << 16);
}

// ---------------------------------------------------------------------------
// Cooperative build: zero+convert -> histogram -> chunk sums -> scan -> fill,
// one kernel, grid.sync() between phases. Replaces 5 dispatches.
// __launch_bounds__(256,4): force VGPR <= 128 so 3 blocks/CU always fit.
__global__ __launch_bounds__(256, 4) void build_kernel(
    const float* __restrict__ x, unsigned short* __restrict__ xb, int total4,
    const float* __restrict__ w0, const float* __restrict__ w1,
    const float* __restrict__ w2, const float* __restrict__ w3,
    const float* __restrict__ w4,
    unsigned short* __restrict__ t0, unsigned short* __restrict__ t1,
    unsigned short* __restrict__ t2, unsigned short* __restrict__ t3,
    unsigned short* __restrict__ t4,
    const int* __restrict__ src, const int* __restrict__ dst,
    int* __restrict__ cnt, int* __restrict__ bsums,
    int* __restrict__ rowptr, int* __restrict__ cursor, int* __restrict__ col,
    int n, int E, int nChunks) {
    cg::grid_group grid = cg::this_grid();
    const int tid = threadIdx.x;
    const int gsz = gridDim.x * 256;
    const int gtid = blockIdx.x * 256 + tid;
    __shared__ int s[256];
    __shared__ int blkoff;

    // ---- P1: zero cnt, convert x -> bf16, convert+transpose 5 weights ----
    for (int i = gtid; i < n; i += gsz) cnt[i] = 0;
    for (int i = gtid; i < total4; i += gsz) {
        float4 v = ((const float4*)x)[i];
        ushort4 o;
        o.x = f2bf(v.x); o.y = f2bf(v.y); o.z = f2bf(v.z); o.w = f2bf(v.w);
        ((ushort4*)xb)[i] = o;
    }
    for (int i = gtid; i < 5 * CH * CH; i += gsz) {
        int wsel = i >> 14;          // 16384 elems per matrix
        int r = i & 16383;
        const float* W; unsigned short* T;
        switch (wsel) {
            case 0: W = w0; T = t0; break;
            case 1: W = w1; T = t1; break;
            case 2: W = w2; T = t2; break;
            case 3: W = w3; T = t3; break;
            default: W = w4; T = t4; break;
        }
        T[(r & 127) * CH + (r >> 7)] = f2bf(W[r]);
    }
    grid.sync();

    // ---- P2: dst-degree histogram ----
    for (int e = gtid; e < E; e += gsz) atomicAdd(&cnt[dst[e]], 1);
    grid.sync();

    // ---- P3: per-chunk (256-elem) partial sums ----
    for (int c = blockIdx.x; c < nChunks; c += gridDim.x) {
        int i = c * 256 + tid;
        s[tid] = (i < n) ? cnt[i] : 0;
        __syncthreads();
#pragma unroll
        for (int off = 128; off > 0; off >>= 1) {
            if (tid < off) s[tid] += s[tid + off];
            __syncthreads();
        }
        if (tid == 0) bsums[c] = s[0];
        __syncthreads();
    }
    grid.sync();

    // ---- P4: per-chunk exclusive scan (+ predecessor offset) ----
    for (int c = blockIdx.x; c < nChunks; c += gridDim.x) {
        s[tid] = (tid < c) ? bsums[tid] : 0;   // c <= nChunks-1 <= 255
        __syncthreads();
#pragma unroll
        for (int off = 128; off > 0; off >>= 1) {
            if (tid < off) s[tid] += s[tid + off];
            __syncthreads();
        }
        if (tid == 0) blkoff = s[0];
        __syncthreads();
        int i = c * 256 + tid;
        int v = (i < n) ? cnt[i] : 0;
        s[tid] = v;
        __syncthreads();
        for (int off = 1; off < 256; off <<= 1) {
            int t = (tid >= off) ? s[tid - off] : 0;
            __syncthreads();
            s[tid] += t;
            __syncthreads();
        }
        if (i < n) {
            int ex = blkoff + s[tid] - v;
            rowptr[i] = ex;
            cursor[i] = ex;
        }
        __syncthreads();
    }
    if (gtid == 0) rowptr[n] = E;
    grid.sync();

    // ---- P5: bucket edges by destination ----
    for (int e = gtid; e < E; e += gsz) {
        int pos = atomicAdd(&cursor[dst[e]], 1);
        col[pos] = src[e];
    }
}

// ---------------------------------------------------------------------------
// Gather: 16 lanes/node (ushort8 = 16B/lane/neighbor), 16 nodes/block,
// unroll 8. Nontemporal agg store (single streamed reader = next GEMM).
__global__ __launch_bounds__(256) void gather_kernel(const unsigned short* __restrict__ feat,
                                                     const int* __restrict__ rowptr,
                                                     const int* __restrict__ col,
                                                     unsigned short* __restrict__ agg, int n) {
    const int node = blockIdx.x * 16 + (threadIdx.x >> 4);
    if (node >= n) return;
    const int c8 = (threadIdx.x & 15) << 3;
    const int beg = rowptr[node];
    const int end = rowptr[node + 1];

    float acc[8];
#pragma unroll
    for (int j = 0; j < 8; ++j) acc[j] = 0.f;

    int i = beg;
    for (; i + 7 < end; i += 8) {
        int s0 = col[i],     s1 = col[i + 1], s2 = col[i + 2], s3 = col[i + 3];
        int s4 = col[i + 4], s5 = col[i + 5], s6 = col[i + 6], s7 = col[i + 7];
        u16x8 v0 = *(const u16x8*)&feat[(size_t)s0 * CH + c8];
        u16x8 v1 = *(const u16x8*)&feat[(size_t)s1 * CH + c8];
        u16x8 v2 = *(const u16x8*)&feat[(size_t)s2 * CH + c8];
        u16x8 v3 = *(const u16x8*)&feat[(size_t)s3 * CH + c8];
        u16x8 v4 = *(const u16x8*)&feat[(size_t)s4 * CH + c8];
        u16x8 v5 = *(const u16x8*)&feat[(size_t)s5 * CH + c8];
        u16x8 v6 = *(const u16x8*)&feat[(size_t)s6 * CH + c8];
        u16x8 v7 = *(const u16x8*)&feat[(size_t)s7 * CH + c8];
#pragma unroll
        for (int j = 0; j < 8; ++j)
            acc[j] += ((bf2f(v0[j]) + bf2f(v1[j])) + (bf2f(v2[j]) + bf2f(v3[j]))) +
                      ((bf2f(v4[j]) + bf2f(v5[j])) + (bf2f(v6[j]) + bf2f(v7[j])));
    }
    for (; i + 1 < end; i += 2) {
        int s0 = col[i], s1 = col[i + 1];
        u16x8 v0 = *(const u16x8*)&feat[(size_t)s0 * CH + c8];
        u16x8 v1 = *(const u16x8*)&feat[(size_t)s1 * CH + c8];
#pragma unroll
        for (int j = 0; j < 8; ++j) acc[j] += bf2f(v0[j]) + bf2f(v1[j]);
    }
    if (i < end) {
        u16x8 v0 = *(const u16x8*)&feat[(size_t)col[i] * CH + c8];
#pragma unroll
        for (int j = 0; j < 8; ++j) acc[j] += bf2f(v0[j]);
    }

    float inv = 1.0f / (float)max(end - beg, 1);
    u16x8 o;
#pragma unroll
    for (int j = 0; j < 8; ++j) o[j] = f2bf(acc[j] * inv);
    __builtin_nontemporal_store(o, (u16x8*)&agg[(size_t)node * CH + c8]);
}

// ---------------------------------------------------------------------------
// MFMA GEMM, no LDS. Block = 256 thr = 4 waves; wave = 32 rows x 128 cols.
// MODE 0: Cb = bf16( relu(A1@Wl + A2@Wr + bias) )
// MODE 1: Cf = alpha*(A1@Wl + bias) + (1-alpha)*bf2f(residb)   [nontemporal out]
template <int MODE>
__global__ __launch_bounds__(256) void mfma_gemm_kernel(
    const unsigned short* __restrict__ A1, const unsigned short* __restrict__ A2,
    const unsigned short* __restrict__ Wt1, const unsigned short* __restrict__ Wt2,
    const float* __restrict__ bias, const float* __restrict__ alpha_p,
    const unsigned short* __restrict__ residb,
    unsigned short* __restrict__ Cb, float* __restrict__ Cf, int n) {
    const int tid = threadIdx.x;
    const int wave = tid >> 6;
    const int lane = tid & 63;
    const int quad = lane >> 4;
    const int l15 = lane & 15;
    const int m0 = blockIdx.x * 128 + wave * 32;

    f32x4 acc[2][8];
#pragma unroll
    for (int t = 0; t < 2; ++t)
#pragma unroll
        for (int u = 0; u < 8; ++u) acc[t][u] = (f32x4){0.f, 0.f, 0.f, 0.f};

    const unsigned short* As[2] = {A1, A2};
    const unsigned short* Ws[2] = {Wt1, Wt2};
    const int nph = (MODE == 0) ? 2 : 1;

    for (int ph = 0; ph < nph; ++ph) {
        const unsigned short* A = As[ph];
        const unsigned short* Wt = Ws[ph];
#pragma unroll
        for (int kb = 0; kb < CH; kb += 32) {
            bf16x8 a[2], b[8];
#pragma unroll
            for (int t = 0; t < 2; ++t) {
                int row = m0 + t * 16 + l15;
                row = min(row, n - 1);                       // clamp; store guarded
                a[t] = *(const bf16x8*)&A[(size_t)row * CH + kb + quad * 8];
            }
#pragma unroll
            for (int u = 0; u < 8; ++u) {
                b[u] = *(const bf16x8*)&Wt[(size_t)(u * 16 + l15) * CH + kb + quad * 8];
            }
#pragma unroll
            for (int t = 0; t < 2; ++t)
#pragma unroll
                for (int u = 0; u < 8; ++u)
                    acc[t][u] = __builtin_amdgcn_mfma_f32_16x16x32_bf16(
                        a[t], b[u], acc[t][u], 0, 0, 0);
        }
    }

    float bv[8];
#pragma unroll
    for (int u = 0; u < 8; ++u) bv[u] = bias[u * 16 + l15];

    float al = 0.f, be = 0.f;
    if (MODE == 1) { al = alpha_p[0]; be = 1.0f - al; }

#pragma unroll
    for (int t = 0; t < 2; ++t) {
#pragma unroll
        for (int r = 0; r < 4; ++r) {
            int row = m0 + t * 16 + quad * 4 + r;
            if (row >= n) continue;
            size_t base = (size_t)row * CH;
#pragma unroll
            for (int u = 0; u < 8; ++u) {
                int colj = u * 16 + l15;
                float v = acc[t][u][r] + bv[u];
                if (MODE == 0) {
                    Cb[base + colj] = f2bf(fmaxf(v, 0.f));
                } else {
                    float o = al * v + be * bf2f(residb[base + colj]);
                    __builtin_nontemporal_store(o, &Cf[base + colj]);
                }
            }
        }
    }
}

// ---------------------------------------------------------------------------
extern "C" void kernel_launch(void* const* d_in, const int* in_sizes, int n_in,
                              void* d_out, int out_size, void* d_ws, size_t ws_size,
                              hipStream_t stream) {
    const float* x    = (const float*)d_in[0];
    const int*   ei   = (const int*)d_in[1];
    const float* W1_l = (const float*)d_in[2];
    const float* b1   = (const float*)d_in[3];
    const float* W1_r = (const float*)d_in[4];
    const float* W2_l = (const float*)d_in[5];
    const float* b2   = (const float*)d_in[6];
    const float* W2_r = (const float*)d_in[7];
    const float* Wd   = (const float*)d_in[8];
    const float* bd   = (const float*)d_in[9];
    const float* alpha = (const float*)d_in[10];
    float* out = (float*)d_out;

    const int n = in_sizes[0] / CH;
    const int E = in_sizes[1] / 2;
    const int* src = ei;
    const int* dst = ei + E;

    const size_t nCH = (size_t)n * CH;
    const int nChunks = (n + 255) / 256;                 // 196 (must be <= 256)

    unsigned short* xb   = (unsigned short*)d_ws;        // [n,CH] bf16 (kept pristine)
    unsigned short* hb   = xb + nCH;                     // [n,CH] bf16
    unsigned short* aggb = hb + nCH;                     // [n,CH] bf16
    unsigned short* ob   = aggb + nCH;                   // [n,CH] bf16 (layer-2 out)
    unsigned short* w1lt = ob + nCH;                     // 5 x [CH,CH] bf16 transposed
    unsigned short* w1rt = w1lt + CH * CH;
    unsigned short* w2lt = w1rt + CH * CH;
    unsigned short* w2rt = w2lt + CH * CH;
    unsigned short* wdt  = w2rt + CH * CH;
    int* cnt    = (int*)(wdt + CH * CH);                 // [n]
    int* rowptr = cnt + n;                               // [n+1]
    int* cursor = rowptr + n + 1;                        // [n]
    int* col    = cursor + n;                            // [E]
    int* bsums  = col + E;                               // [nChunks]

    const int gatherBlocks = (n + 15) / 16;              // 3125
    const int gemmBlocks = (n + 127) / 128;              // 391

    // ---- cooperative CSR build + conversions (1 dispatch) ----
    int total4 = (int)(nCH / 4);
    int n_ = n, E_ = E, nChunks_ = nChunks;
    void* kargs[] = {
        (void*)&x, (void*)&xb, (void*)&total4,
        (void*)&W1_l, (void*)&W1_r, (void*)&W2_l, (void*)&W2_r, (void*)&Wd,
        (void*)&w1lt, (void*)&w1rt, (void*)&w2lt, (void*)&w2rt, (void*)&wdt,
        (void*)&src, (void*)&dst,
        (void*)&cnt, (void*)&bsums, (void*)&rowptr, (void*)&cursor, (void*)&col,
        (void*)&n_, (void*)&E_, (void*)&nChunks_};
    hipLaunchCooperativeKernel((const void*)build_kernel, dim3(BUILD_GRID),
                               dim3(256), kargs, 0, stream);

    // ---- layer 1: hb = relu(agg(xb)@W1_l + xb@W1_r + b1) ----
    gather_kernel<<<gatherBlocks, 256, 0, stream>>>(xb, rowptr, col, aggb, n);
    mfma_gemm_kernel<0><<<gemmBlocks, 256, 0, stream>>>(
        aggb, xb, w1lt, w1rt, b1, nullptr, nullptr, hb, nullptr, n);
    // ---- layer 2: ob = relu(agg(hb)@W2_l + hb@W2_r + b2) ----
    gather_kernel<<<gatherBlocks, 256, 0, stream>>>(hb, rowptr, col, aggb, n);
    mfma_gemm_kernel<0><<<gemmBlocks, 256, 0, stream>>>(
        aggb, hb, w2lt, w2rt, b2, nullptr, nullptr, ob, nullptr, n);
    // ---- decoder + residual: out = alpha*(ob@Wd + bd) + (1-alpha)*xb ----
    mfma_gemm_kernel<1><<<gemmBlocks, 256, 0, stream>>>(
        ob, nullptr, wdt, nullptr, bd, alpha, xb, nullptr, out, n);
}

// Round 10
// 304.218 us; speedup vs baseline: 2.0993x; 2.0993x over previous
//
#include <hip/hip_runtime.h>

#define CH 128
#define SCAN_B 256
#define TM 64            // fused-layer rows per block
#define SPAD (CH + 8)    // LDS row stride (ushorts): 2-way bank alias only

typedef short bf16x8 __attribute__((ext_vector_type(8)));
typedef float f32x4 __attribute__((ext_vector_type(4)));
typedef unsigned short u16x8 __attribute__((ext_vector_type(8)));

static __device__ __forceinline__ unsigned short f2bf(float f) {
    unsigned int u = __float_as_uint(f);
    u = (u + 0x7fff + ((u >> 16) & 1)) >> 16;   // RNE
    return (unsigned short)u;
}
static __device__ __forceinline__ float bf2f(unsigned short s) {
    return __uint_as_float(((unsigned int)s) << 16);
}

// ---------------------------------------------------------------------------
// Fused prep: [0, xBlocks)        : fp32->bf16 feature conversion
//             [xBlocks, +wBlocks) : 5 weight matrices -> bf16 transposed
//             [.., +edgeBlocks)   : dst-degree histogram
__global__ __launch_bounds__(256) void prep_kernel(
    const float* __restrict__ x, unsigned short* __restrict__ xb, int total4,
    const float* __restrict__ w0, const float* __restrict__ w1,
    const float* __restrict__ w2, const float* __restrict__ w3,
    const float* __restrict__ w4,
    unsigned short* __restrict__ t0, unsigned short* __restrict__ t1,
    unsigned short* __restrict__ t2, unsigned short* __restrict__ t3,
    unsigned short* __restrict__ t4,
    const int* __restrict__ dst, int* __restrict__ cnt, int E,
    int xBlocks, int wBlocks) {
    int b = blockIdx.x;
    if (b < xBlocks) {
        int idx = b * 256 + threadIdx.x;
        if (idx < total4) {
            float4 v = ((const float4*)x)[idx];
            ushort4 o;
            o.x = f2bf(v.x); o.y = f2bf(v.y); o.z = f2bf(v.z); o.w = f2bf(v.w);
            ((ushort4*)xb)[idx] = o;
        }
    } else if (b < xBlocks + wBlocks) {
        int idx = (b - xBlocks) * 256 + threadIdx.x;   // 0..81919
        int wsel = idx >> 14;                          // 16384 elems per matrix
        int r = idx & 16383;
        const float* W; unsigned short* T;
        switch (wsel) {
            case 0: W = w0; T = t0; break;
            case 1: W = w1; T = t1; break;
            case 2: W = w2; T = t2; break;
            case 3: W = w3; T = t3; break;
            default: W = w4; T = t4; break;
        }
        T[(r & 127) * CH + (r >> 7)] = f2bf(W[r]);
    } else {
        int e = (b - xBlocks - wBlocks) * 256 + threadIdx.x;
        if (e < E) atomicAdd(&cnt[dst[e]], 1);
    }
}

// ---------------------------------------------------------------------------
__global__ __launch_bounds__(256) void scan_partial_kernel(const int* __restrict__ cnt,
                                                           int* __restrict__ blockSums,
                                                           int n) {
    __shared__ int red[256];
    const int tid = threadIdx.x;
    const int i = blockIdx.x * SCAN_B + tid;
    red[tid] = (i < n) ? cnt[i] : 0;
    __syncthreads();
#pragma unroll
    for (int off = 128; off > 0; off >>= 1) {
        if (tid < off) red[tid] += red[tid + off];
        __syncthreads();
    }
    if (tid == 0) blockSums[blockIdx.x] = red[0];
}

// Fused phase-2 scan: block b reduces predecessors' partials in LDS, then
// local 256-chunk exclusive scan. Requires scanBlocks <= 256.
__global__ __launch_bounds__(256) void scan_final_kernel(const int* __restrict__ cnt,
                                                         const int* __restrict__ blockSums,
                                                         int* __restrict__ rowptr,
                                                         int* __restrict__ cursor,
                                                         int n, int E) {
    __shared__ int s[256];
    __shared__ int blkoff;
    const int tid = threadIdx.x;

    s[tid] = (tid < (int)blockIdx.x) ? blockSums[tid] : 0;
    __syncthreads();
#pragma unroll
    for (int off = 128; off > 0; off >>= 1) {
        if (tid < off) s[tid] += s[tid + off];
        __syncthreads();
    }
    if (tid == 0) blkoff = s[0];
    __syncthreads();

    const int i = blockIdx.x * SCAN_B + tid;
    int v = (i < n) ? cnt[i] : 0;
    s[tid] = v;
    __syncthreads();
    for (int off = 1; off < 256; off <<= 1) {
        int t = (tid >= off) ? s[tid - off] : 0;
        __syncthreads();
        s[tid] += t;
        __syncthreads();
    }
    if (i < n) {
        int ex = blkoff + s[tid] - v;
        rowptr[i] = ex;
        cursor[i] = ex;
    }
    if (blockIdx.x == 0 && tid == 0) rowptr[n] = E;
}

__global__ __launch_bounds__(256) void fill_kernel(const int* __restrict__ src,
                                                   const int* __restrict__ dst,
                                                   int* __restrict__ cursor,
                                                   int* __restrict__ col, int E) {
    int e = blockIdx.x * 256 + threadIdx.x;
    if (e < E) {
        int pos = atomicAdd(&cursor[dst[e]], 1);
        col[pos] = src[e];
    }
}

// ---------------------------------------------------------------------------
// Fused SAGE layer: out = relu( mean_agg(feat) @ Wl + feat @ Wr + bias ).
// Block = 256 thr = 4 waves, 64 rows.
// Phase A: gather 64 nodes' mean-aggregate into LDS (bf16, padded rows).
// Phase B: MFMA — A1 fragments from LDS, A2 (self rows) from global,
//          W from global (L2-hot, pre-transposed [ncol][k]).
__global__ __launch_bounds__(256) void fused_sage_kernel(
    const unsigned short* __restrict__ feat,
    const int* __restrict__ rowptr, const int* __restrict__ col,
    const unsigned short* __restrict__ Wlt, const unsigned short* __restrict__ Wrt,
    const float* __restrict__ bias,
    unsigned short* __restrict__ outb, int n) {
    __shared__ unsigned short sAgg[TM * SPAD];

    const int tid = threadIdx.x;
    const int rowBase = blockIdx.x * TM;

    // ---- Phase A: gather (16 lanes/node, 4 passes of 16 nodes) ----
    const int c8 = (tid & 15) << 3;
#pragma unroll
    for (int pass = 0; pass < 4; ++pass) {
        const int nl = pass * 16 + (tid >> 4);
        const int node = rowBase + nl;
        if (node < n) {
            const int beg = rowptr[node];
            const int end = rowptr[node + 1];
            float acc[8];
#pragma unroll
            for (int j = 0; j < 8; ++j) acc[j] = 0.f;
            int i = beg;
            for (; i + 3 < end; i += 4) {
                int s0 = col[i], s1 = col[i + 1], s2 = col[i + 2], s3 = col[i + 3];
                u16x8 v0 = *(const u16x8*)&feat[(size_t)s0 * CH + c8];
                u16x8 v1 = *(const u16x8*)&feat[(size_t)s1 * CH + c8];
                u16x8 v2 = *(const u16x8*)&feat[(size_t)s2 * CH + c8];
                u16x8 v3 = *(const u16x8*)&feat[(size_t)s3 * CH + c8];
#pragma unroll
                for (int j = 0; j < 8; ++j)
                    acc[j] += (bf2f(v0[j]) + bf2f(v1[j])) + (bf2f(v2[j]) + bf2f(v3[j]));
            }
            for (; i < end; ++i) {
                u16x8 v0 = *(const u16x8*)&feat[(size_t)col[i] * CH + c8];
#pragma unroll
                for (int j = 0; j < 8; ++j) acc[j] += bf2f(v0[j]);
            }
            float inv = 1.0f / (float)max(end - beg, 1);
            u16x8 o;
#pragma unroll
            for (int j = 0; j < 8; ++j) o[j] = f2bf(acc[j] * inv);
            *(u16x8*)&sAgg[nl * SPAD + c8] = o;
        }
    }
    __syncthreads();

    // ---- Phase B: MFMA. Wave w owns rows [w*16, w*16+16) x 128 cols ----
    const int wave = tid >> 6;
    const int lane = tid & 63;
    const int quad = lane >> 4;
    const int l15 = lane & 15;

    f32x4 acc[8];
#pragma unroll
    for (int u = 0; u < 8; ++u) acc[u] = (f32x4){0.f, 0.f, 0.f, 0.f};

#pragma unroll
    for (int kb = 0; kb < CH; kb += 32) {
        // A1 from LDS (aggregate), A2 from global (self rows)
        bf16x8 a1 = *(const bf16x8*)&sAgg[(wave * 16 + l15) * SPAD + kb + quad * 8];
        int row = min(rowBase + wave * 16 + l15, n - 1);
        bf16x8 a2 = *(const bf16x8*)&feat[(size_t)row * CH + kb + quad * 8];
#pragma unroll
        for (int u = 0; u < 8; ++u) {
            bf16x8 bl = *(const bf16x8*)&Wlt[(size_t)(u * 16 + l15) * CH + kb + quad * 8];
            acc[u] = __builtin_amdgcn_mfma_f32_16x16x32_bf16(a1, bl, acc[u], 0, 0, 0);
            bf16x8 br = *(const bf16x8*)&Wrt[(size_t)(u * 16 + l15) * CH + kb + quad * 8];
            acc[u] = __builtin_amdgcn_mfma_f32_16x16x32_bf16(a2, br, acc[u], 0, 0, 0);
        }
    }

    float bv[8];
#pragma unroll
    for (int u = 0; u < 8; ++u) bv[u] = bias[u * 16 + l15];

#pragma unroll
    for (int r = 0; r < 4; ++r) {
        int row = rowBase + wave * 16 + quad * 4 + r;
        if (row >= n) continue;
        size_t base = (size_t)row * CH;
#pragma unroll
        for (int u = 0; u < 8; ++u)
            outb[base + u * 16 + l15] = f2bf(fmaxf(acc[u][r] + bv[u], 0.f));
    }
}

// ---------------------------------------------------------------------------
// Decoder GEMM: out = alpha*(A@Wt + bias) + (1-alpha)*bf2f(residb).
// Block = 256 thr = 4 waves; wave = 32 rows x 128 cols. Nontemporal out.
__global__ __launch_bounds__(256) void decoder_kernel(
    const unsigned short* __restrict__ A, const unsigned short* __restrict__ Wt,
    const float* __restrict__ bias, const float* __restrict__ alpha_p,
    const unsigned short* __restrict__ residb,
    float* __restrict__ Cf, int n) {
    const int tid = threadIdx.x;
    const int wave = tid >> 6;
    const int lane = tid & 63;
    const int quad = lane >> 4;
    const int l15 = lane & 15;
    const int m0 = blockIdx.x * 128 + wave * 32;

    f32x4 acc[2][8];
#pragma unroll
    for (int t = 0; t < 2; ++t)
#pragma unroll
        for (int u = 0; u < 8; ++u) acc[t][u] = (f32x4){0.f, 0.f, 0.f, 0.f};

#pragma unroll
    for (int kb = 0; kb < CH; kb += 32) {
        bf16x8 a[2], b[8];
#pragma unroll
        for (int t = 0; t < 2; ++t) {
            int row = min(m0 + t * 16 + l15, n - 1);
            a[t] = *(const bf16x8*)&A[(size_t)row * CH + kb + quad * 8];
        }
#pragma unroll
        for (int u = 0; u < 8; ++u)
            b[u] = *(const bf16x8*)&Wt[(size_t)(u * 16 + l15) * CH + kb + quad * 8];
#pragma unroll
        for (int t = 0; t < 2; ++t)
#pragma unroll
            for (int u = 0; u < 8; ++u)
                acc[t][u] = __builtin_amdgcn_mfma_f32_16x16x32_bf16(
                    a[t], b[u], acc[t][u], 0, 0, 0);
    }

    float bv[8];
#pragma unroll
    for (int u = 0; u < 8; ++u) bv[u] = bias[u * 16 + l15];
    const float al = alpha_p[0], be = 1.0f - al;

#pragma unroll
    for (int t = 0; t < 2; ++t) {
#pragma unroll
        for (int r = 0; r < 4; ++r) {
            int row = m0 + t * 16 + quad * 4 + r;
            if (row >= n) continue;
            size_t base = (size_t)row * CH;
#pragma unroll
            for (int u = 0; u < 8; ++u) {
                float o = al * (acc[t][u][r] + bv[u]) + be * bf2f(residb[base + u * 16 + l15]);
                __builtin_nontemporal_store(o, &Cf[base + u * 16 + l15]);
            }
        }
    }
}

// ---------------------------------------------------------------------------
extern "C" void kernel_launch(void* const* d_in, const int* in_sizes, int n_in,
                              void* d_out, int out_size, void* d_ws, size_t ws_size,
                              hipStream_t stream) {
    const float* x    = (const float*)d_in[0];
    const int*   ei   = (const int*)d_in[1];
    const float* W1_l = (const float*)d_in[2];
    const float* b1   = (const float*)d_in[3];
    const float* W1_r = (const float*)d_in[4];
    const float* W2_l = (const float*)d_in[5];
    const float* b2   = (const float*)d_in[6];
    const float* W2_r = (const float*)d_in[7];
    const float* Wd   = (const float*)d_in[8];
    const float* bd   = (const float*)d_in[9];
    const float* alpha = (const float*)d_in[10];
    float* out = (float*)d_out;

    const int n = in_sizes[0] / CH;
    const int E = in_sizes[1] / 2;
    const int* src = ei;
    const int* dst = ei + E;

    const size_t nCH = (size_t)n * CH;
    const int scanBlocks = (n + SCAN_B - 1) / SCAN_B;    // 196 (must be <= 256)

    unsigned short* xb   = (unsigned short*)d_ws;        // [n,CH] bf16 (kept pristine)
    unsigned short* hb   = xb + nCH;                     // [n,CH] bf16
    unsigned short* ob   = hb + nCH;                     // [n,CH] bf16 (layer-2 out)
    unsigned short* w1lt = ob + nCH;                     // 5 x [CH,CH] bf16 transposed
    unsigned short* w1rt = w1lt + CH * CH;
    unsigned short* w2lt = w1rt + CH * CH;
    unsigned short* w2rt = w2lt + CH * CH;
    unsigned short* wdt  = w2rt + CH * CH;
    int* cnt    = (int*)(wdt + CH * CH);                 // [n]
    int* rowptr = cnt + n;                               // [n+1]
    int* cursor = rowptr + n + 1;                        // [n]
    int* col    = cursor + n;                            // [E]
    int* bsums  = col + E;                               // [scanBlocks]

    const int edgeBlocks = (E + 255) / 256;              // 2500
    const int xBlocks = (int)((nCH / 4 + 255) / 256);    // 6250
    const int wBlocks = 5 * CH * CH / 256;               // 320
    const int layerBlocks = (n + TM - 1) / TM;           // 782
    const int decBlocks = (n + 127) / 128;               // 391

    // ---- CSR build + conversions (5 small dispatches; coop-fusion regressed R9) ----
    hipMemsetAsync(cnt, 0, (size_t)n * sizeof(int), stream);
    prep_kernel<<<xBlocks + wBlocks + edgeBlocks, 256, 0, stream>>>(
        x, xb, (int)(nCH / 4),
        W1_l, W1_r, W2_l, W2_r, Wd, w1lt, w1rt, w2lt, w2rt, wdt,
        dst, cnt, E, xBlocks, wBlocks);
    scan_partial_kernel<<<scanBlocks, 256, 0, stream>>>(cnt, bsums, n);
    scan_final_kernel<<<scanBlocks, 256, 0, stream>>>(cnt, bsums, rowptr, cursor, n, E);
    fill_kernel<<<edgeBlocks, 256, 0, stream>>>(src, dst, cursor, col, E);

    // ---- layer 1 (fused gather+GEMM): hb = relu(agg(xb)@W1_l + xb@W1_r + b1) ----
    fused_sage_kernel<<<layerBlocks, 256, 0, stream>>>(
        xb, rowptr, col, w1lt, w1rt, b1, hb, n);
    // ---- layer 2: ob = relu(agg(hb)@W2_l + hb@W2_r + b2) ----
    fused_sage_kernel<<<layerBlocks, 256, 0, stream>>>(
        hb, rowptr, col, w2lt, w2rt, b2, ob, n);
    // ---- decoder + residual: out = alpha*(ob@Wd + bd) + (1-alpha)*xb ----
    decoder_kernel<<<decBlocks, 256, 0, stream>>>(ob, wdt, bd, alpha, xb, out, n);
}

// Round 11
// 276.928 us; speedup vs baseline: 2.3062x; 1.0985x over previous
//
#include <hip/hip_runtime.h>

#define CH 128
#define SCAN_B 256

typedef short bf16x8 __attribute__((ext_vector_type(8)));
typedef float f32x4 __attribute__((ext_vector_type(4)));
typedef unsigned short u16x8 __attribute__((ext_vector_type(8)));

static __device__ __forceinline__ unsigned short f2bf(float f) {
    unsigned int u = __float_as_uint(f);
    u = (u + 0x7fff + ((u >> 16) & 1)) >> 16;   // RNE
    return (unsigned short)u;
}
static __device__ __forceinline__ float bf2f(unsigned short s) {
    return __uint_as_float(((unsigned int)s) << 16);
}

// ---------------------------------------------------------------------------
// Fused prep: [0, xBlocks)        : fp32->bf16 feature conversion
//             [xBlocks, +wBlocks) : 5 weight matrices -> bf16 transposed
//             [.., +edgeBlocks)   : dst-degree histogram
__global__ __launch_bounds__(256) void prep_kernel(
    const float* __restrict__ x, unsigned short* __restrict__ xb, int total4,
    const float* __restrict__ w0, const float* __restrict__ w1,
    const float* __restrict__ w2, const float* __restrict__ w3,
    const float* __restrict__ w4,
    unsigned short* __restrict__ t0, unsigned short* __restrict__ t1,
    unsigned short* __restrict__ t2, unsigned short* __restrict__ t3,
    unsigned short* __restrict__ t4,
    const int* __restrict__ dst, int* __restrict__ cnt, int E,
    int xBlocks, int wBlocks) {
    int b = blockIdx.x;
    if (b < xBlocks) {
        int idx = b * 256 + threadIdx.x;
        if (idx < total4) {
            float4 v = ((const float4*)x)[idx];
            ushort4 o;
            o.x = f2bf(v.x); o.y = f2bf(v.y); o.z = f2bf(v.z); o.w = f2bf(v.w);
            ((ushort4*)xb)[idx] = o;
        }
    } else if (b < xBlocks + wBlocks) {
        int idx = (b - xBlocks) * 256 + threadIdx.x;   // 0..81919
        int wsel = idx >> 14;                          // 16384 elems per matrix
        int r = idx & 16383;
        const float* W; unsigned short* T;
        switch (wsel) {
            case 0: W = w0; T = t0; break;
            case 1: W = w1; T = t1; break;
            case 2: W = w2; T = t2; break;
            case 3: W = w3; T = t3; break;
            default: W = w4; T = t4; break;
        }
        T[(r & 127) * CH + (r >> 7)] = f2bf(W[r]);
    } else {
        int e = (b - xBlocks - wBlocks) * 256 + threadIdx.x;
        if (e < E) atomicAdd(&cnt[dst[e]], 1);
    }
}

// ---------------------------------------------------------------------------
__global__ __launch_bounds__(256) void scan_partial_kernel(const int* __restrict__ cnt,
                                                           int* __restrict__ blockSums,
                                                           int n) {
    __shared__ int red[256];
    const int tid = threadIdx.x;
    const int i = blockIdx.x * SCAN_B + tid;
    red[tid] = (i < n) ? cnt[i] : 0;
    __syncthreads();
#pragma unroll
    for (int off = 128; off > 0; off >>= 1) {
        if (tid < off) red[tid] += red[tid + off];
        __syncthreads();
    }
    if (tid == 0) blockSums[blockIdx.x] = red[0];
}

// Fused phase-2 scan: block b reduces predecessors' partials in LDS, then
// local 256-chunk exclusive scan. Requires scanBlocks <= 256.
__global__ __launch_bounds__(256) void scan_final_kernel(const int* __restrict__ cnt,
                                                         const int* __restrict__ blockSums,
                                                         int* __restrict__ rowptr,
                                                         int* __restrict__ cursor,
                                                         int n, int E) {
    __shared__ int s[256];
    __shared__ int blkoff;
    const int tid = threadIdx.x;

    s[tid] = (tid < (int)blockIdx.x) ? blockSums[tid] : 0;
    __syncthreads();
#pragma unroll
    for (int off = 128; off > 0; off >>= 1) {
        if (tid < off) s[tid] += s[tid + off];
        __syncthreads();
    }
    if (tid == 0) blkoff = s[0];
    __syncthreads();

    const int i = blockIdx.x * SCAN_B + tid;
    int v = (i < n) ? cnt[i] : 0;
    s[tid] = v;
    __syncthreads();
    for (int off = 1; off < 256; off <<= 1) {
        int t = (tid >= off) ? s[tid - off] : 0;
        __syncthreads();
        s[tid] += t;
        __syncthreads();
    }
    if (i < n) {
        int ex = blkoff + s[tid] - v;
        rowptr[i] = ex;
        cursor[i] = ex;
    }
    if (blockIdx.x == 0 && tid == 0) rowptr[n] = E;
}

__global__ __launch_bounds__(256) void fill_kernel(const int* __restrict__ src,
                                                   const int* __restrict__ dst,
                                                   int* __restrict__ cursor,
                                                   int* __restrict__ col, int E) {
    int e = blockIdx.x * 256 + threadIdx.x;
    if (e < E) {
        int pos = atomicAdd(&cursor[dst[e]], 1);
        col[pos] = src[e];
    }
}

// ---------------------------------------------------------------------------
// Gather: 16 lanes/node (ushort8 = 16B/lane/neighbor), 16 nodes/block,
// unroll 8. NT loads for col (read-once stream), NT store for agg
// (single streamed reader = next GEMM) — keep L2 for the feat table.
__global__ __launch_bounds__(256) void gather_kernel(const unsigned short* __restrict__ feat,
                                                     const int* __restrict__ rowptr,
                                                     const int* __restrict__ col,
                                                     unsigned short* __restrict__ agg, int n) {
    const int node = blockIdx.x * 16 + (threadIdx.x >> 4);
    if (node >= n) return;
    const int c8 = (threadIdx.x & 15) << 3;
    const int beg = rowptr[node];
    const int end = rowptr[node + 1];

    float acc[8];
#pragma unroll
    for (int j = 0; j < 8; ++j) acc[j] = 0.f;

    int i = beg;
    for (; i + 7 < end; i += 8) {
        int s0 = __builtin_nontemporal_load(&col[i]);
        int s1 = __builtin_nontemporal_load(&col[i + 1]);
        int s2 = __builtin_nontemporal_load(&col[i + 2]);
        int s3 = __builtin_nontemporal_load(&col[i + 3]);
        int s4 = __builtin_nontemporal_load(&col[i + 4]);
        int s5 = __builtin_nontemporal_load(&col[i + 5]);
        int s6 = __builtin_nontemporal_load(&col[i + 6]);
        int s7 = __builtin_nontemporal_load(&col[i + 7]);
        u16x8 v0 = *(const u16x8*)&feat[(size_t)s0 * CH + c8];
        u16x8 v1 = *(const u16x8*)&feat[(size_t)s1 * CH + c8];
        u16x8 v2 = *(const u16x8*)&feat[(size_t)s2 * CH + c8];
        u16x8 v3 = *(const u16x8*)&feat[(size_t)s3 * CH + c8];
        u16x8 v4 = *(const u16x8*)&feat[(size_t)s4 * CH + c8];
        u16x8 v5 = *(const u16x8*)&feat[(size_t)s5 * CH + c8];
        u16x8 v6 = *(const u16x8*)&feat[(size_t)s6 * CH + c8];
        u16x8 v7 = *(const u16x8*)&feat[(size_t)s7 * CH + c8];
#pragma unroll
        for (int j = 0; j < 8; ++j)
            acc[j] += ((bf2f(v0[j]) + bf2f(v1[j])) + (bf2f(v2[j]) + bf2f(v3[j]))) +
                      ((bf2f(v4[j]) + bf2f(v5[j])) + (bf2f(v6[j]) + bf2f(v7[j])));
    }
    for (; i + 1 < end; i += 2) {
        int s0 = col[i], s1 = col[i + 1];
        u16x8 v0 = *(const u16x8*)&feat[(size_t)s0 * CH + c8];
        u16x8 v1 = *(const u16x8*)&feat[(size_t)s1 * CH + c8];
#pragma unroll
        for (int j = 0; j < 8; ++j) acc[j] += bf2f(v0[j]) + bf2f(v1[j]);
    }
    if (i < end) {
        u16x8 v0 = *(const u16x8*)&feat[(size_t)col[i] * CH + c8];
#pragma unroll
        for (int j = 0; j < 8; ++j) acc[j] += bf2f(v0[j]);
    }

    float inv = 1.0f / (float)max(end - beg, 1);
    u16x8 o;
#pragma unroll
    for (int j = 0; j < 8; ++j) o[j] = f2bf(acc[j] * inv);
    __builtin_nontemporal_store(o, (u16x8*)&agg[(size_t)node * CH + c8]);
}

// ---------------------------------------------------------------------------
// MFMA GEMM, no LDS. Block = 256 thr = 4 waves; wave = 32 rows x 128 cols.
// MODE 0: Cb = bf16( relu(A1@Wl + A2@Wr + bias) )
// MODE 1: Cf = alpha*(A1@Wl + bias) + (1-alpha)*bf2f(residb)   [NT out]
template <int MODE>
__global__ __launch_bounds__(256) void mfma_gemm_kernel(
    const unsigned short* __restrict__ A1, const unsigned short* __restrict__ A2,
    const unsigned short* __restrict__ Wt1, const unsigned short* __restrict__ Wt2,
    const float* __restrict__ bias, const float* __restrict__ alpha_p,
    const unsigned short* __restrict__ residb,
    unsigned short* __restrict__ Cb, float* __restrict__ Cf, int n) {
    const int tid = threadIdx.x;
    const int wave = tid >> 6;
    const int lane = tid & 63;
    const int quad = lane >> 4;
    const int l15 = lane & 15;
    const int m0 = blockIdx.x * 128 + wave * 32;

    f32x4 acc[2][8];
#pragma unroll
    for (int t = 0; t < 2; ++t)
#pragma unroll
        for (int u = 0; u < 8; ++u) acc[t][u] = (f32x4){0.f, 0.f, 0.f, 0.f};

    const unsigned short* As[2] = {A1, A2};
    const unsigned short* Ws[2] = {Wt1, Wt2};
    const int nph = (MODE == 0) ? 2 : 1;

    for (int ph = 0; ph < nph; ++ph) {
        const unsigned short* A = As[ph];
        const unsigned short* Wt = Ws[ph];
#pragma unroll
        for (int kb = 0; kb < CH; kb += 32) {
            bf16x8 a[2], b[8];
#pragma unroll
            for (int t = 0; t < 2; ++t) {
                int row = m0 + t * 16 + l15;
                row = min(row, n - 1);                       // clamp; store guarded
                a[t] = *(const bf16x8*)&A[(size_t)row * CH + kb + quad * 8];
            }
#pragma unroll
            for (int u = 0; u < 8; ++u) {
                b[u] = *(const bf16x8*)&Wt[(size_t)(u * 16 + l15) * CH + kb + quad * 8];
            }
#pragma unroll
            for (int t = 0; t < 2; ++t)
#pragma unroll
                for (int u = 0; u < 8; ++u)
                    acc[t][u] = __builtin_amdgcn_mfma_f32_16x16x32_bf16(
                        a[t], b[u], acc[t][u], 0, 0, 0);
        }
    }

    float bv[8];
#pragma unroll
    for (int u = 0; u < 8; ++u) bv[u] = bias[u * 16 + l15];

    float al = 0.f, be = 0.f;
    if (MODE == 1) { al = alpha_p[0]; be = 1.0f - al; }

#pragma unroll
    for (int t = 0; t < 2; ++t) {
#pragma unroll
        for (int r = 0; r < 4; ++r) {
            int row = m0 + t * 16 + quad * 4 + r;
            if (row >= n) continue;
            size_t base = (size_t)row * CH;
#pragma unroll
            for (int u = 0; u < 8; ++u) {
                int colj = u * 16 + l15;
                float v = acc[t][u][r] + bv[u];
                if (MODE == 0) {
                    Cb[base + colj] = f2bf(fmaxf(v, 0.f));
                } else {
                    float o = al * v + be * bf2f(residb[base + colj]);
                    __builtin_nontemporal_store(o, &Cf[base + colj]);
                }
            }
        }
    }
}

// ---------------------------------------------------------------------------
extern "C" void kernel_launch(void* const* d_in, const int* in_sizes, int n_in,
                              void* d_out, int out_size, void* d_ws, size_t ws_size,
                              hipStream_t stream) {
    const float* x    = (const float*)d_in[0];
    const int*   ei   = (const int*)d_in[1];
    const float* W1_l = (const float*)d_in[2];
    const float* b1   = (const float*)d_in[3];
    const float* W1_r = (const float*)d_in[4];
    const float* W2_l = (const float*)d_in[5];
    const float* b2   = (const float*)d_in[6];
    const float* W2_r = (const float*)d_in[7];
    const float* Wd   = (const float*)d_in[8];
    const float* bd   = (const float*)d_in[9];
    const float* alpha = (const float*)d_in[10];
    float* out = (float*)d_out;

    const int n = in_sizes[0] / CH;
    const int E = in_sizes[1] / 2;
    const int* src = ei;
    const int* dst = ei + E;

    const size_t nCH = (size_t)n * CH;
    const int scanBlocks = (n + SCAN_B - 1) / SCAN_B;    // 196 (must be <= 256)

    unsigned short* xb   = (unsigned short*)d_ws;        // [n,CH] bf16 (kept pristine)
    unsigned short* hb   = xb + nCH;                     // [n,CH] bf16
    unsigned short* aggb = hb + nCH;                     // [n,CH] bf16
    unsigned short* ob   = aggb + nCH;                   // [n,CH] bf16 (layer-2 out)
    unsigned short* w1lt = ob + nCH;                     // 5 x [CH,CH] bf16 transposed
    unsigned short* w1rt = w1lt + CH * CH;
    unsigned short* w2lt = w1rt + CH * CH;
    unsigned short* w2rt = w2lt + CH * CH;
    unsigned short* wdt  = w2rt + CH * CH;
    int* cnt    = (int*)(wdt + CH * CH);                 // [n]
    int* rowptr = cnt + n;                               // [n+1]
    int* cursor = rowptr + n + 1;                        // [n]
    int* col    = cursor + n;                            // [E]
    int* bsums  = col + E;                               // [scanBlocks]

    const int edgeBlocks = (E + 255) / 256;              // 2500
    const int xBlocks = (int)((nCH / 4 + 255) / 256);    // 6250
    const int wBlocks = 5 * CH * CH / 256;               // 320
    const int gatherBlocks = (n + 15) / 16;              // 3125
    const int gemmBlocks = (n + 127) / 128;              // 391

    // ---- CSR build + conversions (small dispatches; fusion regressed R9/R10) ----
    hipMemsetAsync(cnt, 0, (size_t)n * sizeof(int), stream);
    prep_kernel<<<xBlocks + wBlocks + edgeBlocks, 256, 0, stream>>>(
        x, xb, (int)(nCH / 4),
        W1_l, W1_r, W2_l, W2_r, Wd, w1lt, w1rt, w2lt, w2rt, wdt,
        dst, cnt, E, xBlocks, wBlocks);
    scan_partial_kernel<<<scanBlocks, 256, 0, stream>>>(cnt, bsums, n);
    scan_final_kernel<<<scanBlocks, 256, 0, stream>>>(cnt, bsums, rowptr, cursor, n, E);
    fill_kernel<<<edgeBlocks, 256, 0, stream>>>(src, dst, cursor, col, E);

    // ---- layer 1: hb = relu(agg(xb)@W1_l + xb@W1_r + b1) ----
    gather_kernel<<<gatherBlocks, 256, 0, stream>>>(xb, rowptr, col, aggb, n);
    mfma_gemm_kernel<0><<<gemmBlocks, 256, 0, stream>>>(
        aggb, xb, w1lt, w1rt, b1, nullptr, nullptr, hb, nullptr, n);
    // ---- layer 2: ob = relu(agg(hb)@W2_l + hb@W2_r + b2) ----
    gather_kernel<<<gatherBlocks, 256, 0, stream>>>(hb, rowptr, col, aggb, n);
    mfma_gemm_kernel<0><<<gemmBlocks, 256, 0, stream>>>(
        aggb, hb, w2lt, w2rt, b2, nullptr, nullptr, ob, nullptr, n);
    // ---- decoder + residual: out = alpha*(ob@Wd + bd) + (1-alpha)*xb ----
    mfma_gemm_kernel<1><<<gemmBlocks, 256, 0, stream>>>(
        ob, nullptr, wdt, nullptr, bd, alpha, xb, nullptr, out, n);
}

// Round 12
// 272.016 us; speedup vs baseline: 2.3479x; 1.0181x over previous
//
#include <hip/hip_runtime.h>

#define CH 128
#define SCAN_B 256
#define SPAD 136   // LDS row stride in ushorts (+16B pad -> 2-way bank alias = free)

typedef short bf16x8 __attribute__((ext_vector_type(8)));
typedef float f32x4 __attribute__((ext_vector_type(4)));
typedef unsigned short u16x8 __attribute__((ext_vector_type(8)));

static __device__ __forceinline__ unsigned short f2bf(float f) {
    unsigned int u = __float_as_uint(f);
    u = (u + 0x7fff + ((u >> 16) & 1)) >> 16;   // RNE
    return (unsigned short)u;
}
static __device__ __forceinline__ float bf2f(unsigned short s) {
    return __uint_as_float(((unsigned int)s) << 16);
}

// ---------------------------------------------------------------------------
// Fused prep: [0, xBlocks)        : fp32->bf16 feature conversion
//             [xBlocks, +wBlocks) : 5 weight matrices -> bf16 transposed
//             [.., +edgeBlocks)   : dst-degree histogram
__global__ __launch_bounds__(256) void prep_kernel(
    const float* __restrict__ x, unsigned short* __restrict__ xb, int total4,
    const float* __restrict__ w0, const float* __restrict__ w1,
    const float* __restrict__ w2, const float* __restrict__ w3,
    const float* __restrict__ w4,
    unsigned short* __restrict__ t0, unsigned short* __restrict__ t1,
    unsigned short* __restrict__ t2, unsigned short* __restrict__ t3,
    unsigned short* __restrict__ t4,
    const int* __restrict__ dst, int* __restrict__ cnt, int E,
    int xBlocks, int wBlocks) {
    int b = blockIdx.x;
    if (b < xBlocks) {
        int idx = b * 256 + threadIdx.x;
        if (idx < total4) {
            float4 v = ((const float4*)x)[idx];
            ushort4 o;
            o.x = f2bf(v.x); o.y = f2bf(v.y); o.z = f2bf(v.z); o.w = f2bf(v.w);
            ((ushort4*)xb)[idx] = o;
        }
    } else if (b < xBlocks + wBlocks) {
        int idx = (b - xBlocks) * 256 + threadIdx.x;   // 0..81919
        int wsel = idx >> 14;                          // 16384 elems per matrix
        int r = idx & 16383;
        const float* W; unsigned short* T;
        switch (wsel) {
            case 0: W = w0; T = t0; break;
            case 1: W = w1; T = t1; break;
            case 2: W = w2; T = t2; break;
            case 3: W = w3; T = t3; break;
            default: W = w4; T = t4; break;
        }
        T[(r & 127) * CH + (r >> 7)] = f2bf(W[r]);
    } else {
        int e = (b - xBlocks - wBlocks) * 256 + threadIdx.x;
        if (e < E) atomicAdd(&cnt[dst[e]], 1);
    }
}

// ---------------------------------------------------------------------------
__global__ __launch_bounds__(256) void scan_partial_kernel(const int* __restrict__ cnt,
                                                           int* __restrict__ blockSums,
                                                           int n) {
    __shared__ int red[256];
    const int tid = threadIdx.x;
    const int i = blockIdx.x * SCAN_B + tid;
    red[tid] = (i < n) ? cnt[i] : 0;
    __syncthreads();
#pragma unroll
    for (int off = 128; off > 0; off >>= 1) {
        if (tid < off) red[tid] += red[tid + off];
        __syncthreads();
    }
    if (tid == 0) blockSums[blockIdx.x] = red[0];
}

// Fused phase-2 scan: block b reduces predecessors' partials in LDS, then
// local 256-chunk exclusive scan. Requires scanBlocks <= 256.
__global__ __launch_bounds__(256) void scan_final_kernel(const int* __restrict__ cnt,
                                                         const int* __restrict__ blockSums,
                                                         int* __restrict__ rowptr,
                                                         int* __restrict__ cursor,
                                                         int n, int E) {
    __shared__ int s[256];
    __shared__ int blkoff;
    const int tid = threadIdx.x;

    s[tid] = (tid < (int)blockIdx.x) ? blockSums[tid] : 0;
    __syncthreads();
#pragma unroll
    for (int off = 128; off > 0; off >>= 1) {
        if (tid < off) s[tid] += s[tid + off];
        __syncthreads();
    }
    if (tid == 0) blkoff = s[0];
    __syncthreads();

    const int i = blockIdx.x * SCAN_B + tid;
    int v = (i < n) ? cnt[i] : 0;
    s[tid] = v;
    __syncthreads();
    for (int off = 1; off < 256; off <<= 1) {
        int t = (tid >= off) ? s[tid - off] : 0;
        __syncthreads();
        s[tid] += t;
        __syncthreads();
    }
    if (i < n) {
        int ex = blkoff + s[tid] - v;
        rowptr[i] = ex;
        cursor[i] = ex;
    }
    if (blockIdx.x == 0 && tid == 0) rowptr[n] = E;
}

__global__ __launch_bounds__(256) void fill_kernel(const int* __restrict__ src,
                                                   const int* __restrict__ dst,
                                                   int* __restrict__ cursor,
                                                   int* __restrict__ col, int E) {
    int e = blockIdx.x * 256 + threadIdx.x;
    if (e < E) {
        int pos = atomicAdd(&cursor[dst[e]], 1);
        col[pos] = src[e];
    }
}

// ---------------------------------------------------------------------------
// Gather: 16 lanes/node (ushort8 = 16B/lane/neighbor), 16 nodes/block, unroll 8.
__global__ __launch_bounds__(256) void gather_kernel(const unsigned short* __restrict__ feat,
                                                     const int* __restrict__ rowptr,
                                                     const int* __restrict__ col,
                                                     unsigned short* __restrict__ agg, int n) {
    const int node = blockIdx.x * 16 + (threadIdx.x >> 4);
    if (node >= n) return;
    const int c8 = (threadIdx.x & 15) << 3;
    const int beg = rowptr[node];
    const int end = rowptr[node + 1];

    float acc[8];
#pragma unroll
    for (int j = 0; j < 8; ++j) acc[j] = 0.f;

    int i = beg;
    for (; i + 7 < end; i += 8) {
        int s0 = col[i],     s1 = col[i + 1], s2 = col[i + 2], s3 = col[i + 3];
        int s4 = col[i + 4], s5 = col[i + 5], s6 = col[i + 6], s7 = col[i + 7];
        u16x8 v0 = *(const u16x8*)&feat[(size_t)s0 * CH + c8];
        u16x8 v1 = *(const u16x8*)&feat[(size_t)s1 * CH + c8];
        u16x8 v2 = *(const u16x8*)&feat[(size_t)s2 * CH + c8];
        u16x8 v3 = *(const u16x8*)&feat[(size_t)s3 * CH + c8];
        u16x8 v4 = *(const u16x8*)&feat[(size_t)s4 * CH + c8];
        u16x8 v5 = *(const u16x8*)&feat[(size_t)s5 * CH + c8];
        u16x8 v6 = *(const u16x8*)&feat[(size_t)s6 * CH + c8];
        u16x8 v7 = *(const u16x8*)&feat[(size_t)s7 * CH + c8];
#pragma unroll
        for (int j = 0; j < 8; ++j)
            acc[j] += ((bf2f(v0[j]) + bf2f(v1[j])) + (bf2f(v2[j]) + bf2f(v3[j]))) +
                      ((bf2f(v4[j]) + bf2f(v5[j])) + (bf2f(v6[j]) + bf2f(v7[j])));
    }
    for (; i + 1 < end; i += 2) {
        int s0 = col[i], s1 = col[i + 1];
        u16x8 v0 = *(const u16x8*)&feat[(size_t)s0 * CH + c8];
        u16x8 v1 = *(const u16x8*)&feat[(size_t)s1 * CH + c8];
#pragma unroll
        for (int j = 0; j < 8; ++j) acc[j] += bf2f(v0[j]) + bf2f(v1[j]);
    }
    if (i < end) {
        u16x8 v0 = *(const u16x8*)&feat[(size_t)col[i] * CH + c8];
#pragma unroll
        for (int j = 0; j < 8; ++j) acc[j] += bf2f(v0[j]);
    }

    float inv = 1.0f / (float)max(end - beg, 1);
    u16x8 o;
#pragma unroll
    for (int j = 0; j < 8; ++j) o[j] = f2bf(acc[j] * inv);
    *(u16x8*)&agg[(size_t)node * CH + c8] = o;
}

// ---------------------------------------------------------------------------
// SAGE layer GEMM (layer 1): Cb = bf16( relu(A1@Wl + A2@Wr + bias) ).
// Block = 256 thr = 4 waves; wave = 32 rows x 128 cols. No LDS.
__global__ __launch_bounds__(256) void sage_gemm_kernel(
    const unsigned short* __restrict__ A1, const unsigned short* __restrict__ A2,
    const unsigned short* __restrict__ Wt1, const unsigned short* __restrict__ Wt2,
    const float* __restrict__ bias,
    unsigned short* __restrict__ Cb, int n) {
    const int tid = threadIdx.x;
    const int wave = tid >> 6;
    const int lane = tid & 63;
    const int quad = lane >> 4;
    const int l15 = lane & 15;
    const int m0 = blockIdx.x * 128 + wave * 32;

    f32x4 acc[2][8];
#pragma unroll
    for (int t = 0; t < 2; ++t)
#pragma unroll
        for (int u = 0; u < 8; ++u) acc[t][u] = (f32x4){0.f, 0.f, 0.f, 0.f};

    const unsigned short* As[2] = {A1, A2};
    const unsigned short* Ws[2] = {Wt1, Wt2};

    for (int ph = 0; ph < 2; ++ph) {
        const unsigned short* A = As[ph];
        const unsigned short* Wt = Ws[ph];
#pragma unroll
        for (int kb = 0; kb < CH; kb += 32) {
            bf16x8 a[2], b[8];
#pragma unroll
            for (int t = 0; t < 2; ++t) {
                int row = min(m0 + t * 16 + l15, n - 1);     // clamp; store guarded
                a[t] = *(const bf16x8*)&A[(size_t)row * CH + kb + quad * 8];
            }
#pragma unroll
            for (int u = 0; u < 8; ++u)
                b[u] = *(const bf16x8*)&Wt[(size_t)(u * 16 + l15) * CH + kb + quad * 8];
#pragma unroll
            for (int t = 0; t < 2; ++t)
#pragma unroll
                for (int u = 0; u < 8; ++u)
                    acc[t][u] = __builtin_amdgcn_mfma_f32_16x16x32_bf16(
                        a[t], b[u], acc[t][u], 0, 0, 0);
        }
    }

    float bv[8];
#pragma unroll
    for (int u = 0; u < 8; ++u) bv[u] = bias[u * 16 + l15];

#pragma unroll
    for (int t = 0; t < 2; ++t) {
#pragma unroll
        for (int r = 0; r < 4; ++r) {
            int row = m0 + t * 16 + quad * 4 + r;
            if (row >= n) continue;
            size_t base = (size_t)row * CH;
#pragma unroll
            for (int u = 0; u < 8; ++u)
                Cb[base + u * 16 + l15] = f2bf(fmaxf(acc[t][u][r] + bv[u], 0.f));
        }
    }
}

// ---------------------------------------------------------------------------
// Fused layer-2 + decoder. Block = 256 thr = 4 waves, 128 rows.
// Phase 1: ob_tile = relu(A1@W2l + A2@W2r + b2) -> LDS (bf16, padded rows).
// Phase 2: out = alpha*(ob_tile@Wd + bd) + (1-alpha)*bf2f(xb).
// Each wave reads only LDS rows it wrote (wave w owns local rows
// [w*32, w*32+32) in both phases) -> NO __syncthreads needed; wave-internal
// lgkmcnt ordering (compiler-inserted) covers the LDS write->read dependency.
__global__ __launch_bounds__(256) void sage_dec_kernel(
    const unsigned short* __restrict__ A1, const unsigned short* __restrict__ A2,
    const unsigned short* __restrict__ Wt1, const unsigned short* __restrict__ Wt2,
    const float* __restrict__ bias2,
    const unsigned short* __restrict__ Wdt, const float* __restrict__ biasd,
    const float* __restrict__ alpha_p, const unsigned short* __restrict__ residb,
    float* __restrict__ Cf, int n) {
    __shared__ unsigned short sOb[128 * SPAD];   // 34.8 KB

    const int tid = threadIdx.x;
    const int wave = tid >> 6;
    const int lane = tid & 63;
    const int quad = lane >> 4;
    const int l15 = lane & 15;
    const int m0 = blockIdx.x * 128 + wave * 32;
    const int lrow0 = wave * 32;                 // this wave's local row base

    // ---- Phase 1: layer-2 SAGE GEMM -> LDS ----
    {
        f32x4 acc[2][8];
#pragma unroll
        for (int t = 0; t < 2; ++t)
#pragma unroll
            for (int u = 0; u < 8; ++u) acc[t][u] = (f32x4){0.f, 0.f, 0.f, 0.f};

        const unsigned short* As[2] = {A1, A2};
        const unsigned short* Ws[2] = {Wt1, Wt2};
        for (int ph = 0; ph < 2; ++ph) {
            const unsigned short* A = As[ph];
            const unsigned short* Wt = Ws[ph];
#pragma unroll
            for (int kb = 0; kb < CH; kb += 32) {
                bf16x8 a[2], b[8];
#pragma unroll
                for (int t = 0; t < 2; ++t) {
                    int row = min(m0 + t * 16 + l15, n - 1);
                    a[t] = *(const bf16x8*)&A[(size_t)row * CH + kb + quad * 8];
                }
#pragma unroll
                for (int u = 0; u < 8; ++u)
                    b[u] = *(const bf16x8*)&Wt[(size_t)(u * 16 + l15) * CH + kb + quad * 8];
#pragma unroll
                for (int t = 0; t < 2; ++t)
#pragma unroll
                    for (int u = 0; u < 8; ++u)
                        acc[t][u] = __builtin_amdgcn_mfma_f32_16x16x32_bf16(
                            a[t], b[u], acc[t][u], 0, 0, 0);
            }
        }

        float bv[8];
#pragma unroll
        for (int u = 0; u < 8; ++u) bv[u] = bias2[u * 16 + l15];

#pragma unroll
        for (int t = 0; t < 2; ++t)
#pragma unroll
            for (int r = 0; r < 4; ++r) {
                int lr = lrow0 + t * 16 + quad * 4 + r;      // local row < 128
#pragma unroll
                for (int u = 0; u < 8; ++u)
                    sOb[lr * SPAD + u * 16 + l15] =
                        f2bf(fmaxf(acc[t][u][r] + bv[u], 0.f));
            }
    }
    // No barrier: each wave reads back only its own 32 LDS rows below.

    // ---- Phase 2: decoder GEMM, A from LDS ----
    {
        f32x4 acc[2][8];
#pragma unroll
        for (int t = 0; t < 2; ++t)
#pragma unroll
            for (int u = 0; u < 8; ++u) acc[t][u] = (f32x4){0.f, 0.f, 0.f, 0.f};

#pragma unroll
        for (int kb = 0; kb < CH; kb += 32) {
            bf16x8 a[2], b[8];
#pragma unroll
            for (int t = 0; t < 2; ++t)
                a[t] = *(const bf16x8*)&sOb[(lrow0 + t * 16 + l15) * SPAD + kb + quad * 8];
#pragma unroll
            for (int u = 0; u < 8; ++u)
                b[u] = *(const bf16x8*)&Wdt[(size_t)(u * 16 + l15) * CH + kb + quad * 8];
#pragma unroll
            for (int t = 0; t < 2; ++t)
#pragma unroll
                for (int u = 0; u < 8; ++u)
                    acc[t][u] = __builtin_amdgcn_mfma_f32_16x16x32_bf16(
                        a[t], b[u], acc[t][u], 0, 0, 0);
        }

        float bv[8];
#pragma unroll
        for (int u = 0; u < 8; ++u) bv[u] = biasd[u * 16 + l15];
        const float al = alpha_p[0], be = 1.0f - al;

#pragma unroll
        for (int t = 0; t < 2; ++t)
#pragma unroll
            for (int r = 0; r < 4; ++r) {
                int row = m0 + t * 16 + quad * 4 + r;
                if (row >= n) continue;
                size_t base = (size_t)row * CH;
#pragma unroll
                for (int u = 0; u < 8; ++u) {
                    int colj = u * 16 + l15;
                    Cf[base + colj] = al * (acc[t][u][r] + bv[u]) +
                                      be * bf2f(residb[base + colj]);
                }
            }
    }
}

// ---------------------------------------------------------------------------
extern "C" void kernel_launch(void* const* d_in, const int* in_sizes, int n_in,
                              void* d_out, int out_size, void* d_ws, size_t ws_size,
                              hipStream_t stream) {
    const float* x    = (const float*)d_in[0];
    const int*   ei   = (const int*)d_in[1];
    const float* W1_l = (const float*)d_in[2];
    const float* b1   = (const float*)d_in[3];
    const float* W1_r = (const float*)d_in[4];
    const float* W2_l = (const float*)d_in[5];
    const float* b2   = (const float*)d_in[6];
    const float* W2_r = (const float*)d_in[7];
    const float* Wd   = (const float*)d_in[8];
    const float* bd   = (const float*)d_in[9];
    const float* alpha = (const float*)d_in[10];
    float* out = (float*)d_out;

    const int n = in_sizes[0] / CH;
    const int E = in_sizes[1] / 2;
    const int* src = ei;
    const int* dst = ei + E;

    const size_t nCH = (size_t)n * CH;
    const int scanBlocks = (n + SCAN_B - 1) / SCAN_B;    // 196 (must be <= 256)

    unsigned short* xb   = (unsigned short*)d_ws;        // [n,CH] bf16 (kept pristine)
    unsigned short* hb   = xb + nCH;                     // [n,CH] bf16
    unsigned short* aggb = hb + nCH;                     // [n,CH] bf16
    unsigned short* w1lt = aggb + nCH;                   // 5 x [CH,CH] bf16 transposed
    unsigned short* w1rt = w1lt + CH * CH;
    unsigned short* w2lt = w1rt + CH * CH;
    unsigned short* w2rt = w2lt + CH * CH;
    unsigned short* wdt  = w2rt + CH * CH;
    int* cnt    = (int*)(wdt + CH * CH);                 // [n]
    int* rowptr = cnt + n;                               // [n+1]
    int* cursor = rowptr + n + 1;                        // [n]
    int* col    = cursor + n;                            // [E]
    int* bsums  = col + E;                               // [scanBlocks]

    const int edgeBlocks = (E + 255) / 256;              // 2500
    const int xBlocks = (int)((nCH / 4 + 255) / 256);    // 6250
    const int wBlocks = 5 * CH * CH / 256;               // 320
    const int gatherBlocks = (n + 15) / 16;              // 3125
    const int gemmBlocks = (n + 127) / 128;              // 391

    // ---- CSR build + conversions ----
    hipMemsetAsync(cnt, 0, (size_t)n * sizeof(int), stream);
    prep_kernel<<<xBlocks + wBlocks + edgeBlocks, 256, 0, stream>>>(
        x, xb, (int)(nCH / 4),
        W1_l, W1_r, W2_l, W2_r, Wd, w1lt, w1rt, w2lt, w2rt, wdt,
        dst, cnt, E, xBlocks, wBlocks);
    scan_partial_kernel<<<scanBlocks, 256, 0, stream>>>(cnt, bsums, n);
    scan_final_kernel<<<scanBlocks, 256, 0, stream>>>(cnt, bsums, rowptr, cursor, n, E);
    fill_kernel<<<edgeBlocks, 256, 0, stream>>>(src, dst, cursor, col, E);

    // ---- layer 1: hb = relu(agg(xb)@W1_l + xb@W1_r + b1) ----
    gather_kernel<<<gatherBlocks, 256, 0, stream>>>(xb, rowptr, col, aggb, n);
    sage_gemm_kernel<<<gemmBlocks, 256, 0, stream>>>(
        aggb, xb, w1lt, w1rt, b1, hb, n);
    // ---- layer 2 + decoder (fused; ob never hits global):
    //      out = alpha*(relu(agg(hb)@W2_l + hb@W2_r + b2)@Wd + bd) + (1-alpha)*xb
    gather_kernel<<<gatherBlocks, 256, 0, stream>>>(hb, rowptr, col, aggb, n);
    sage_dec_kernel<<<gemmBlocks, 256, 0, stream>>>(
        aggb, hb, w2lt, w2rt, b2, wdt, bd, alpha, xb, out, n);
}

// Round 13
// 269.477 us; speedup vs baseline: 2.3700x; 1.0094x over previous
//
#include <hip/hip_runtime.h>

#define CH 128
#define SCAN_B 256
#define SPAD 136   // LDS row stride in ushorts (+16B pad -> 2-way bank alias = free)

typedef short bf16x8 __attribute__((ext_vector_type(8)));
typedef float f32x4 __attribute__((ext_vector_type(4)));
typedef unsigned short u16x8 __attribute__((ext_vector_type(8)));

static __device__ __forceinline__ unsigned short f2bf(float f) {
    unsigned int u = __float_as_uint(f);
    u = (u + 0x7fff + ((u >> 16) & 1)) >> 16;   // RNE
    return (unsigned short)u;
}
static __device__ __forceinline__ float bf2f(unsigned short s) {
    return __uint_as_float(((unsigned int)s) << 16);
}

// ---------------------------------------------------------------------------
// Fused prep: [0, xBlocks)        : fp32->bf16 feature conversion
//             [xBlocks, +wBlocks) : 5 weight matrices -> bf16 transposed
//             [.., +edgeBlocks)   : dst-degree histogram
__global__ __launch_bounds__(256) void prep_kernel(
    const float* __restrict__ x, unsigned short* __restrict__ xb, int total4,
    const float* __restrict__ w0, const float* __restrict__ w1,
    const float* __restrict__ w2, const float* __restrict__ w3,
    const float* __restrict__ w4,
    unsigned short* __restrict__ t0, unsigned short* __restrict__ t1,
    unsigned short* __restrict__ t2, unsigned short* __restrict__ t3,
    unsigned short* __restrict__ t4,
    const int* __restrict__ dst, int* __restrict__ cnt, int E,
    int xBlocks, int wBlocks) {
    int b = blockIdx.x;
    if (b < xBlocks) {
        int idx = b * 256 + threadIdx.x;
        if (idx < total4) {
            float4 v = ((const float4*)x)[idx];
            ushort4 o;
            o.x = f2bf(v.x); o.y = f2bf(v.y); o.z = f2bf(v.z); o.w = f2bf(v.w);
            ((ushort4*)xb)[idx] = o;
        }
    } else if (b < xBlocks + wBlocks) {
        int idx = (b - xBlocks) * 256 + threadIdx.x;   // 0..81919
        int wsel = idx >> 14;                          // 16384 elems per matrix
        int r = idx & 16383;
        const float* W; unsigned short* T;
        switch (wsel) {
            case 0: W = w0; T = t0; break;
            case 1: W = w1; T = t1; break;
            case 2: W = w2; T = t2; break;
            case 3: W = w3; T = t3; break;
            default: W = w4; T = t4; break;
        }
        T[(r & 127) * CH + (r >> 7)] = f2bf(W[r]);
    } else {
        int e = (b - xBlocks - wBlocks) * 256 + threadIdx.x;
        if (e < E) atomicAdd(&cnt[dst[e]], 1);
    }
}

// ---------------------------------------------------------------------------
__global__ __launch_bounds__(256) void scan_partial_kernel(const int* __restrict__ cnt,
                                                           int* __restrict__ blockSums,
                                                           int n) {
    __shared__ int red[256];
    const int tid = threadIdx.x;
    const int i = blockIdx.x * SCAN_B + tid;
    red[tid] = (i < n) ? cnt[i] : 0;
    __syncthreads();
#pragma unroll
    for (int off = 128; off > 0; off >>= 1) {
        if (tid < off) red[tid] += red[tid + off];
        __syncthreads();
    }
    if (tid == 0) blockSums[blockIdx.x] = red[0];
}

// Fused phase-2 scan: block b reduces predecessors' partials in LDS, then
// local 256-chunk exclusive scan. Requires scanBlocks <= 256.
__global__ __launch_bounds__(256) void scan_final_kernel(const int* __restrict__ cnt,
                                                         const int* __restrict__ blockSums,
                                                         int* __restrict__ rowptr,
                                                         int* __restrict__ cursor,
                                                         int n, int E) {
    __shared__ int s[256];
    __shared__ int blkoff;
    const int tid = threadIdx.x;

    s[tid] = (tid < (int)blockIdx.x) ? blockSums[tid] : 0;
    __syncthreads();
#pragma unroll
    for (int off = 128; off > 0; off >>= 1) {
        if (tid < off) s[tid] += s[tid + off];
        __syncthreads();
    }
    if (tid == 0) blkoff = s[0];
    __syncthreads();

    const int i = blockIdx.x * SCAN_B + tid;
    int v = (i < n) ? cnt[i] : 0;
    s[tid] = v;
    __syncthreads();
    for (int off = 1; off < 256; off <<= 1) {
        int t = (tid >= off) ? s[tid - off] : 0;
        __syncthreads();
        s[tid] += t;
        __syncthreads();
    }
    if (i < n) {
        int ex = blkoff + s[tid] - v;
        rowptr[i] = ex;
        cursor[i] = ex;
    }
    if (blockIdx.x == 0 && tid == 0) rowptr[n] = E;
}

__global__ __launch_bounds__(256) void fill_kernel(const int* __restrict__ src,
                                                   const int* __restrict__ dst,
                                                   int* __restrict__ cursor,
                                                   int* __restrict__ col, int E) {
    int e = blockIdx.x * 256 + threadIdx.x;
    if (e < E) {
        int pos = atomicAdd(&cursor[dst[e]], 1);
        col[pos] = src[e];
    }
}

// ---------------------------------------------------------------------------
// Gather v4: 32 lanes/node, split into 2 x 16-lane half-groups taking
// even/odd neighbors (halves serial depth + straggler tail), lane owns
// 8 channels (16B loads). Cross-half combine via shfl_xor(16). 8 nodes/block.
__global__ __launch_bounds__(256) void gather_kernel(const unsigned short* __restrict__ feat,
                                                     const int* __restrict__ rowptr,
                                                     const int* __restrict__ col,
                                                     unsigned short* __restrict__ agg, int n) {
    const int node = blockIdx.x * 8 + (threadIdx.x >> 5);
    if (node >= n) return;
    const int lane5 = threadIdx.x & 31;     // position within the node's 32 lanes
    const int g = lane5 >> 4;               // half-group: 0 = even edges, 1 = odd
    const int c8 = (lane5 & 15) << 3;
    const int beg = rowptr[node];
    const int end = rowptr[node + 1];

    float acc[8];
#pragma unroll
    for (int j = 0; j < 8; ++j) acc[j] = 0.f;

    int i = beg + g;
    for (; i + 6 < end; i += 8) {           // 4 neighbors/lane/iter (stride 2)
        int s0 = col[i], s1 = col[i + 2], s2 = col[i + 4], s3 = col[i + 6];
        u16x8 v0 = *(const u16x8*)&feat[(size_t)s0 * CH + c8];
        u16x8 v1 = *(const u16x8*)&feat[(size_t)s1 * CH + c8];
        u16x8 v2 = *(const u16x8*)&feat[(size_t)s2 * CH + c8];
        u16x8 v3 = *(const u16x8*)&feat[(size_t)s3 * CH + c8];
#pragma unroll
        for (int j = 0; j < 8; ++j)
            acc[j] += (bf2f(v0[j]) + bf2f(v1[j])) + (bf2f(v2[j]) + bf2f(v3[j]));
    }
    for (; i < end; i += 2) {
        u16x8 v0 = *(const u16x8*)&feat[(size_t)col[i] * CH + c8];
#pragma unroll
        for (int j = 0; j < 8; ++j) acc[j] += bf2f(v0[j]);
    }

    // combine the two half-group partials (lane ^ 16 stays within the node)
#pragma unroll
    for (int j = 0; j < 8; ++j) acc[j] += __shfl_xor(acc[j], 16, 64);

    if (g == 0) {
        float inv = 1.0f / (float)max(end - beg, 1);
        u16x8 o;
#pragma unroll
        for (int j = 0; j < 8; ++j) o[j] = f2bf(acc[j] * inv);
        *(u16x8*)&agg[(size_t)node * CH + c8] = o;
    }
}

// ---------------------------------------------------------------------------
// SAGE layer GEMM (layer 1): Cb = bf16( relu(A1@Wl + A2@Wr + bias) ).
// Block = 256 thr = 4 waves; wave = 32 rows x 128 cols. No LDS.
__global__ __launch_bounds__(256) void sage_gemm_kernel(
    const unsigned short* __restrict__ A1, const unsigned short* __restrict__ A2,
    const unsigned short* __restrict__ Wt1, const unsigned short* __restrict__ Wt2,
    const float* __restrict__ bias,
    unsigned short* __restrict__ Cb, int n) {
    const int tid = threadIdx.x;
    const int wave = tid >> 6;
    const int lane = tid & 63;
    const int quad = lane >> 4;
    const int l15 = lane & 15;
    const int m0 = blockIdx.x * 128 + wave * 32;

    f32x4 acc[2][8];
#pragma unroll
    for (int t = 0; t < 2; ++t)
#pragma unroll
        for (int u = 0; u < 8; ++u) acc[t][u] = (f32x4){0.f, 0.f, 0.f, 0.f};

    const unsigned short* As[2] = {A1, A2};
    const unsigned short* Ws[2] = {Wt1, Wt2};

    for (int ph = 0; ph < 2; ++ph) {
        const unsigned short* A = As[ph];
        const unsigned short* Wt = Ws[ph];
#pragma unroll
        for (int kb = 0; kb < CH; kb += 32) {
            bf16x8 a[2], b[8];
#pragma unroll
            for (int t = 0; t < 2; ++t) {
                int row = min(m0 + t * 16 + l15, n - 1);     // clamp; store guarded
                a[t] = *(const bf16x8*)&A[(size_t)row * CH + kb + quad * 8];
            }
#pragma unroll
            for (int u = 0; u < 8; ++u)
                b[u] = *(const bf16x8*)&Wt[(size_t)(u * 16 + l15) * CH + kb + quad * 8];
#pragma unroll
            for (int t = 0; t < 2; ++t)
#pragma unroll
                for (int u = 0; u < 8; ++u)
                    acc[t][u] = __builtin_amdgcn_mfma_f32_16x16x32_bf16(
                        a[t], b[u], acc[t][u], 0, 0, 0);
        }
    }

    float bv[8];
#pragma unroll
    for (int u = 0; u < 8; ++u) bv[u] = bias[u * 16 + l15];

#pragma unroll
    for (int t = 0; t < 2; ++t) {
#pragma unroll
        for (int r = 0; r < 4; ++r) {
            int row = m0 + t * 16 + quad * 4 + r;
            if (row >= n) continue;
            size_t base = (size_t)row * CH;
#pragma unroll
            for (int u = 0; u < 8; ++u)
                Cb[base + u * 16 + l15] = f2bf(fmaxf(acc[t][u][r] + bv[u], 0.f));
        }
    }
}

// ---------------------------------------------------------------------------
// Fused layer-2 + decoder. Block = 256 thr = 4 waves, 128 rows.
// Phase 1: ob_tile = relu(A1@W2l + A2@W2r + b2) -> LDS (bf16, padded rows).
// Phase 2: out = alpha*(ob_tile@Wd + bd) + (1-alpha)*bf2f(xb).
// Each wave reads only LDS rows it wrote -> no __syncthreads needed.
__global__ __launch_bounds__(256) void sage_dec_kernel(
    const unsigned short* __restrict__ A1, const unsigned short* __restrict__ A2,
    const unsigned short* __restrict__ Wt1, const unsigned short* __restrict__ Wt2,
    const float* __restrict__ bias2,
    const unsigned short* __restrict__ Wdt, const float* __restrict__ biasd,
    const float* __restrict__ alpha_p, const unsigned short* __restrict__ residb,
    float* __restrict__ Cf, int n) {
    __shared__ unsigned short sOb[128 * SPAD];   // 34.8 KB

    const int tid = threadIdx.x;
    const int wave = tid >> 6;
    const int lane = tid & 63;
    const int quad = lane >> 4;
    const int l15 = lane & 15;
    const int m0 = blockIdx.x * 128 + wave * 32;
    const int lrow0 = wave * 32;                 // this wave's local row base

    // ---- Phase 1: layer-2 SAGE GEMM -> LDS ----
    {
        f32x4 acc[2][8];
#pragma unroll
        for (int t = 0; t < 2; ++t)
#pragma unroll
            for (int u = 0; u < 8; ++u) acc[t][u] = (f32x4){0.f, 0.f, 0.f, 0.f};

        const unsigned short* As[2] = {A1, A2};
        const unsigned short* Ws[2] = {Wt1, Wt2};
        for (int ph = 0; ph < 2; ++ph) {
            const unsigned short* A = As[ph];
            const unsigned short* Wt = Ws[ph];
#pragma unroll
            for (int kb = 0; kb < CH; kb += 32) {
                bf16x8 a[2], b[8];
#pragma unroll
                for (int t = 0; t < 2; ++t) {
                    int row = min(m0 + t * 16 + l15, n - 1);
                    a[t] = *(const bf16x8*)&A[(size_t)row * CH + kb + quad * 8];
                }
#pragma unroll
                for (int u = 0; u < 8; ++u)
                    b[u] = *(const bf16x8*)&Wt[(size_t)(u * 16 + l15) * CH + kb + quad * 8];
#pragma unroll
                for (int t = 0; t < 2; ++t)
#pragma unroll
                    for (int u = 0; u < 8; ++u)
                        acc[t][u] = __builtin_amdgcn_mfma_f32_16x16x32_bf16(
                            a[t], b[u], acc[t][u], 0, 0, 0);
            }
        }

        float bv[8];
#pragma unroll
        for (int u = 0; u < 8; ++u) bv[u] = bias2[u * 16 + l15];

#pragma unroll
        for (int t = 0; t < 2; ++t)
#pragma unroll
            for (int r = 0; r < 4; ++r) {
                int lr = lrow0 + t * 16 + quad * 4 + r;      // local row < 128
#pragma unroll
                for (int u = 0; u < 8; ++u)
                    sOb[lr * SPAD + u * 16 + l15] =
                        f2bf(fmaxf(acc[t][u][r] + bv[u], 0.f));
            }
    }
    // No barrier: each wave reads back only its own 32 LDS rows below.

    // ---- Phase 2: decoder GEMM, A from LDS ----
    {
        f32x4 acc[2][8];
#pragma unroll
        for (int t = 0; t < 2; ++t)
#pragma unroll
            for (int u = 0; u < 8; ++u) acc[t][u] = (f32x4){0.f, 0.f, 0.f, 0.f};

#pragma unroll
        for (int kb = 0; kb < CH; kb += 32) {
            bf16x8 a[2], b[8];
#pragma unroll
            for (int t = 0; t < 2; ++t)
                a[t] = *(const bf16x8*)&sOb[(lrow0 + t * 16 + l15) * SPAD + kb + quad * 8];
#pragma unroll
            for (int u = 0; u < 8; ++u)
                b[u] = *(const bf16x8*)&Wdt[(size_t)(u * 16 + l15) * CH + kb + quad * 8];
#pragma unroll
            for (int t = 0; t < 2; ++t)
#pragma unroll
                for (int u = 0; u < 8; ++u)
                    acc[t][u] = __builtin_amdgcn_mfma_f32_16x16x32_bf16(
                        a[t], b[u], acc[t][u], 0, 0, 0);
        }

        float bv[8];
#pragma unroll
        for (int u = 0; u < 8; ++u) bv[u] = biasd[u * 16 + l15];
        const float al = alpha_p[0], be = 1.0f - al;

#pragma unroll
        for (int t = 0; t < 2; ++t)
#pragma unroll
            for (int r = 0; r < 4; ++r) {
                int row = m0 + t * 16 + quad * 4 + r;
                if (row >= n) continue;
                size_t base = (size_t)row * CH;
#pragma unroll
                for (int u = 0; u < 8; ++u) {
                    int colj = u * 16 + l15;
                    Cf[base + colj] = al * (acc[t][u][r] + bv[u]) +
                                      be * bf2f(residb[base + colj]);
                }
            }
    }
}

// ---------------------------------------------------------------------------
extern "C" void kernel_launch(void* const* d_in, const int* in_sizes, int n_in,
                              void* d_out, int out_size, void* d_ws, size_t ws_size,
                              hipStream_t stream) {
    const float* x    = (const float*)d_in[0];
    const int*   ei   = (const int*)d_in[1];
    const float* W1_l = (const float*)d_in[2];
    const float* b1   = (const float*)d_in[3];
    const float* W1_r = (const float*)d_in[4];
    const float* W2_l = (const float*)d_in[5];
    const float* b2   = (const float*)d_in[6];
    const float* W2_r = (const float*)d_in[7];
    const float* Wd   = (const float*)d_in[8];
    const float* bd   = (const float*)d_in[9];
    const float* alpha = (const float*)d_in[10];
    float* out = (float*)d_out;

    const int n = in_sizes[0] / CH;
    const int E = in_sizes[1] / 2;
    const int* src = ei;
    const int* dst = ei + E;

    const size_t nCH = (size_t)n * CH;
    const int scanBlocks = (n + SCAN_B - 1) / SCAN_B;    // 196 (must be <= 256)

    unsigned short* xb   = (unsigned short*)d_ws;        // [n,CH] bf16 (kept pristine)
    unsigned short* hb   = xb + nCH;                     // [n,CH] bf16
    unsigned short* aggb = hb + nCH;                     // [n,CH] bf16
    unsigned short* w1lt = aggb + nCH;                   // 5 x [CH,CH] bf16 transposed
    unsigned short* w1rt = w1lt + CH * CH;
    unsigned short* w2lt = w1rt + CH * CH;
    unsigned short* w2rt = w2lt + CH * CH;
    unsigned short* wdt  = w2rt + CH * CH;
    int* cnt    = (int*)(wdt + CH * CH);                 // [n]
    int* rowptr = cnt + n;                               // [n+1]
    int* cursor = rowptr + n + 1;                        // [n]
    int* col    = cursor + n;                            // [E]
    int* bsums  = col + E;                               // [scanBlocks]

    const int edgeBlocks = (E + 255) / 256;              // 2500
    const int xBlocks = (int)((nCH / 4 + 255) / 256);    // 6250
    const int wBlocks = 5 * CH * CH / 256;               // 320
    const int gatherBlocks = (n + 7) / 8;                // 6250
    const int gemmBlocks = (n + 127) / 128;              // 391

    // ---- CSR build + conversions ----
    hipMemsetAsync(cnt, 0, (size_t)n * sizeof(int), stream);
    prep_kernel<<<xBlocks + wBlocks + edgeBlocks, 256, 0, stream>>>(
        x, xb, (int)(nCH / 4),
        W1_l, W1_r, W2_l, W2_r, Wd, w1lt, w1rt, w2lt, w2rt, wdt,
        dst, cnt, E, xBlocks, wBlocks);
    scan_partial_kernel<<<scanBlocks, 256, 0, stream>>>(cnt, bsums, n);
    scan_final_kernel<<<scanBlocks, 256, 0, stream>>>(cnt, bsums, rowptr, cursor, n, E);
    fill_kernel<<<edgeBlocks, 256, 0, stream>>>(src, dst, cursor, col, E);

    // ---- layer 1: hb = relu(agg(xb)@W1_l + xb@W1_r + b1) ----
    gather_kernel<<<gatherBlocks, 256, 0, stream>>>(xb, rowptr, col, aggb, n);
    sage_gemm_kernel<<<gemmBlocks, 256, 0, stream>>>(
        aggb, xb, w1lt, w1rt, b1, hb, n);
    // ---- layer 2 + decoder (fused; ob never hits global):
    //      out = alpha*(relu(agg(hb)@W2_l + hb@W2_r + b2)@Wd + bd) + (1-alpha)*xb
    gather_kernel<<<gatherBlocks, 256, 0, stream>>>(hb, rowptr, col, aggb, n);
    sage_dec_kernel<<<gemmBlocks, 256, 0, stream>>>(
        aggb, hb, w2lt, w2rt, b2, wdt, bd, alpha, xb, out, n);
}